// Round 4
// baseline (273.056 us; speedup 1.0000x reference)
//
#include <hip/hip_runtime.h>

#define STEPS 30
#define HID 32
#define NG 16                    // 16 half2 groups = 32 hidden units per lane
#define TPB 64                   // one wave per block: barrier is just a waitcnt
#define EPB TPB                  // 1 lane per element
#define LDS_STRIDE (STEPS + 1)   // 31: odd stride -> conflict-free row reads/writes

typedef _Float16 h2 __attribute__((ext_vector_type(2)));

// v_cvt_pkrtz_f16_f32: one instruction packs two f32 -> half2.
static __device__ __forceinline__ h2 pkrtz(float x, float y) {
    return __builtin_bit_cast(h2, __builtin_amdgcn_cvt_pkrtz(x, y));
}
// v_pk_fma_f16 (full-rate VOP3P on 32-bit regs)
static __device__ __forceinline__ h2 h2fma(h2 a, h2 b, h2 c) {
    return __builtin_elementwise_fma(a, b, c);
}
// v_pk_max_f16
static __device__ __forceinline__ h2 h2max(h2 a, h2 b) {
    return __builtin_elementwise_max(a, b);
}

__global__ __launch_bounds__(TPB, 4) void hedge_kernel(
    const float* __restrict__ S,
    const float* __restrict__ W1,
    const float* __restrict__ b1,
    const float* __restrict__ W2,
    const float* __restrict__ b2,
    const float* __restrict__ a_init,
    float* __restrict__ out)
{
    __shared__ float tile[EPB * LDS_STRIDE];   // 64*31*4 = 7936 B
    const int tid  = threadIdx.x;
    const long long base = (long long)blockIdx.x * (EPB * STEPS);

    // ---- Stage S tile (64 elems x 30 steps) coalesced via float2 into padded LDS ----
    const float2* S2 = (const float2*)(S + base);
    #pragma unroll
    for (int k = 0; k < (EPB * STEPS) / (2 * TPB); ++k) {   // 15 iters
        int i2 = tid + k * TPB;            // float2 index in [0, 960)
        float2 v = S2[i2];
        int row = i2 / 15;                 // = (2*i2)/30
        int col = 2 * (i2 - row * 15);     // even, <= 28: pair stays within a row
        float* p = &tile[row * LDS_STRIDE + col];
        p[0] = v.x; p[1] = v.y;
    }

    // ---- Full 32-unit weight set per lane, packed half2 (wave-uniform values) ----
    h2 wa[NG], wc[NG], we[NG], wb[NG], w2[NG];
    #pragma unroll
    for (int q = 0; q < 8; ++q) {                         // 8 float4 = 32 floats/array
        float4 va = ((const float4*)(W1 + 0 * HID))[q];   // coeff of s
        float4 vc = ((const float4*)(W1 + 1 * HID))[q];   // coeff of d_prev
        float4 ve = ((const float4*)(W1 + 2 * HID))[q];   // coeff of h
        float4 vb = ((const float4*)(b1))[q];
        float4 v2 = ((const float4*)(W2))[q];
        wa[2*q] = pkrtz(va.x, va.y); wa[2*q+1] = pkrtz(va.z, va.w);
        wc[2*q] = pkrtz(vc.x, vc.y); wc[2*q+1] = pkrtz(vc.z, vc.w);
        we[2*q] = pkrtz(ve.x, ve.y); we[2*q+1] = pkrtz(ve.z, ve.w);
        wb[2*q] = pkrtz(vb.x, vb.y); wb[2*q+1] = pkrtz(vb.z, vb.w);
        w2[2*q] = pkrtz(v2.x, v2.y); w2[2*q+1] = pkrtz(v2.z, v2.w);
    }
    const float bias2 = b2[0];
    float d = a_init[0];                       // fp32 carries
    float h = 0.0f;
    const h2 zero2 = {(_Float16)0.0f, (_Float16)0.0f};
    __syncthreads();                           // 1-wave block: lgkmcnt fence

    // ---- Recurrence: 1 lane = 1 element, 32 units/lane. No cross-lane ops at all:
    //      serial chain is pure VALU (~10 ops/step). 5 VOP3P per 2 units + dot2 f32 acc. ----
    float* my = &tile[tid * LDS_STRIDE];
    #pragma unroll
    for (int t = 0; t < STEPS; ++t) {
        const float s = my[t];                 // conflict-free: bank = (t - tid) mod 32
        const h2 s2v = pkrtz(s, s);
        const h2 d2v = pkrtz(d, d);
        const h2 h2v = pkrtz(h, h);
        float a0 = bias2, a1 = 0.f, a2 = 0.f, a3 = 0.f;   // bias folded into acc init
        #pragma unroll
        for (int g = 0; g < NG; g += 4) {
            h2 t0 = h2fma(wa[g+0], s2v, h2fma(wc[g+0], d2v, h2fma(we[g+0], h2v, wb[g+0])));
            h2 t1 = h2fma(wa[g+1], s2v, h2fma(wc[g+1], d2v, h2fma(we[g+1], h2v, wb[g+1])));
            h2 t2 = h2fma(wa[g+2], s2v, h2fma(wc[g+2], d2v, h2fma(we[g+2], h2v, wb[g+2])));
            h2 t3 = h2fma(wa[g+3], s2v, h2fma(wc[g+3], d2v, h2fma(we[g+3], h2v, wb[g+3])));
            // v_dot2_f32_f16: exact f16 products, fp32 accumulate
            a0 = __builtin_amdgcn_fdot2(h2max(t0, zero2), w2[g+0], a0, false);
            a1 = __builtin_amdgcn_fdot2(h2max(t1, zero2), w2[g+1], a1, false);
            a2 = __builtin_amdgcn_fdot2(h2max(t2, zero2), w2[g+2], a2, false);
            a3 = __builtin_amdgcn_fdot2(h2max(t3, zero2), w2[g+3], a3, false);
        }
        const float dn = (a0 + a1) + (a2 + a3);   // full d_t in-lane, no shuffle
        h = fmaf(0.2f, dn, 0.8f * h);
        d = dn;
        my[t] = dn;                            // S[t] consumed; slot reused for output
    }
    __syncthreads();                           // order writes before cross-lane dump

    // ---- Dump outputs coalesced via float2 (same flat layout as S) ----
    float2* O2 = (float2*)(out + base);
    #pragma unroll
    for (int k = 0; k < (EPB * STEPS) / (2 * TPB); ++k) {   // 15 iters
        int i2 = tid + k * TPB;
        int row = i2 / 15;
        int col = 2 * (i2 - row * 15);
        const float* p = &tile[row * LDS_STRIDE + col];
        O2[i2] = make_float2(p[0], p[1]);
    }
}

extern "C" void kernel_launch(void* const* d_in, const int* in_sizes, int n_in,
                              void* d_out, int out_size, void* d_ws, size_t ws_size,
                              hipStream_t stream) {
    const float* S      = (const float*)d_in[0];
    const float* W1     = (const float*)d_in[1];
    const float* b1     = (const float*)d_in[2];
    const float* W2     = (const float*)d_in[3];
    const float* b2     = (const float*)d_in[4];
    const float* a_init = (const float*)d_in[5];
    float* out = (float*)d_out;

    const int batch = in_sizes[0] / STEPS;    // 1048576
    const int grid  = batch / EPB;            // 16384 blocks of 64 elements
    hedge_kernel<<<grid, TPB, 0, stream>>>(S, W1, b1, W2, b2, a_init, out);
}

// Round 5
// 259.648 us; speedup vs baseline: 1.0516x; 1.0516x over previous
//
#include <hip/hip_runtime.h>

#define STEPS 30
#define HID 32
#define TPB 256
#define EPB 128                  // 128 elements per block: 4 waves x 32 elems/wave
#define LDS_STRIDE (STEPS + 1)   // 31: odd stride -> conflict-free per-element column reads

typedef float f32x16 __attribute__((ext_vector_type(16)));
typedef __fp16 h8 __attribute__((ext_vector_type(8)));
typedef unsigned int u32x4 __attribute__((ext_vector_type(4)));

// v_cvt_pkrtz_f16_f32 -> packed (lo=x, hi=y) as one 32-bit reg
static __device__ __forceinline__ unsigned int pkrtz_u32(float x, float y) {
    return __builtin_bit_cast(unsigned int, __builtin_amdgcn_cvt_pkrtz(x, y));
}

__global__ __launch_bounds__(TPB, 4) void hedge_kernel(
    const float* __restrict__ S,
    const float* __restrict__ W1,
    const float* __restrict__ b1,
    const float* __restrict__ W2,
    const float* __restrict__ b2,
    const float* __restrict__ a_init,
    float* __restrict__ out)
{
    __shared__ float tile[EPB * LDS_STRIDE];   // 128*31*4 = 15872 B
    const int tid  = threadIdx.x;
    const int lane = tid & 63;
    const int wv   = tid >> 6;                 // wave id 0..3, owns elems 32*wv..32*wv+31
    const long long base = (long long)blockIdx.x * (EPB * STEPS);

    // ---- Stage S tile (128 elems x 30 steps) coalesced into padded LDS ----
    #pragma unroll
    for (int k = 0; k < (EPB * STEPS) / TPB; ++k) {   // 15 iters
        int idx = tid + k * TPB;
        float v = S[base + idx];
        int row = idx / STEPS;
        int col = idx - row * STEPS;
        tile[row * LDS_STRIDE + col] = v;
    }

    // ---- A fragment (constant): W1^aug (32 units x K=16), biases in k0 row.
    //      mfma_f32_32x32x16_f16 A layout: row m = lane&31, k = (lane>>5)*8 + {0..7}.
    //      Lanes<32 hold k=0..3 = (wb, wa, wc, we), k=4..7 = 0; lanes>=32 (k=8..15) all 0.
    //      The zeros in A make every unused B slot harmless. ----
    const int j = lane & 31;
    const float wbf = b1[j];
    const float waf = W1[0 * HID + j];         // coeff of s
    const float wcf = W1[1 * HID + j];         // coeff of d_prev
    const float wef = W1[2 * HID + j];         // coeff of h
    u32x4 av;
    if (lane < 32) {
        av[0] = pkrtz_u32(wbf, waf);           // k0=bias-row(1), k1=s
        av[1] = pkrtz_u32(wcf, wef);           // k2=d, k3=h
        av[2] = 0u; av[3] = 0u;                // k4..7 dead
    } else {
        av[0] = 0u; av[1] = 0u; av[2] = 0u; av[3] = 0u;   // k8..15 dead
    }
    const h8 afrag = __builtin_bit_cast(h8, av);

    // ---- Per-lane W2 slice matching the C/D row map:
    //      row(reg r) = (r&3) + 8*(r>>2) + 4*(lane>>5) ----
    const int rbase = 4 * (lane >> 5);
    float w2r[16];
    #pragma unroll
    for (int r = 0; r < 16; ++r)
        w2r[r] = W2[(r & 3) + 8 * (r >> 2) + rbase];

    const float bias2 = b2[0];
    float d = a_init[0];                       // fp32 carries
    float h = 0.0f;
    const f32x16 zero16 = {0.f};               // loop-invariant C operand
    __syncthreads();

    // ---- Recurrence: one wave = 32 elements. Per step:
    //      1 MFMA (layer 1, fp32 accum) + fp32 VALU layer 2 + 1 shfl to merge halves.
    //      MFMA col = lane&31 == element -> d lands in the lane that feeds next B. ----
    float* my = &tile[(32 * wv + (lane & 31)) * LDS_STRIDE];
    #pragma unroll
    for (int t = 0; t < STEPS; ++t) {
        const float s = my[t];                 // bank = (t - lane) mod 32: conflict-free
        u32x4 bv;
        bv[0] = pkrtz_u32(1.0f, s);            // k0=1 (bias), k1=s
        bv[1] = pkrtz_u32(d, h);               // k2=d, k3=h
        bv[2] = bv[0]; bv[3] = bv[1];          // dead slots (A zeros)
        const h8 bfrag = __builtin_bit_cast(h8, bv);

        const f32x16 P = __builtin_amdgcn_mfma_f32_32x32x16_f16(afrag, bfrag, zero16, 0, 0, 0);

        float a0 = 0.f, a1 = 0.f, a2 = 0.f, a3 = 0.f;
        #pragma unroll
        for (int r = 0; r < 16; r += 4) {
            a0 = fmaf(w2r[r + 0], fmaxf(P[r + 0], 0.f), a0);
            a1 = fmaf(w2r[r + 1], fmaxf(P[r + 1], 0.f), a1);
            a2 = fmaf(w2r[r + 2], fmaxf(P[r + 2], 0.f), a2);
            a3 = fmaf(w2r[r + 3], fmaxf(P[r + 3], 0.f), a3);
        }
        float part = (a0 + a1) + (a2 + a3);    // this half-wave's 16 units
        part += __shfl_xor(part, 32);          // + other half's 16 units
        const float dn = bias2 + part;         // every lane: full d_t for its element
        h = fmaf(0.2f, dn, 0.8f * h);
        d = dn;
        my[t] = dn;                            // S[t] consumed; slot reused for output
    }
    __syncthreads();

    // ---- Dump outputs coalesced (same flat layout as S) ----
    #pragma unroll
    for (int k = 0; k < (EPB * STEPS) / TPB; ++k) {   // 15 iters
        int idx = tid + k * TPB;
        int row = idx / STEPS;
        int col = idx - row * STEPS;
        out[base + idx] = tile[row * LDS_STRIDE + col];
    }
}

extern "C" void kernel_launch(void* const* d_in, const int* in_sizes, int n_in,
                              void* d_out, int out_size, void* d_ws, size_t ws_size,
                              hipStream_t stream) {
    const float* S      = (const float*)d_in[0];
    const float* W1     = (const float*)d_in[1];
    const float* b1     = (const float*)d_in[2];
    const float* W2     = (const float*)d_in[3];
    const float* b2     = (const float*)d_in[4];
    const float* a_init = (const float*)d_in[5];
    float* out = (float*)d_out;

    const int batch = in_sizes[0] / STEPS;    // 1048576
    const int grid  = batch / EPB;            // 8192 blocks of 128 elements
    hedge_kernel<<<grid, TPB, 0, stream>>>(S, W1, b1, W2, b2, a_init, out);
}

// Round 6
// 252.940 us; speedup vs baseline: 1.0795x; 1.0265x over previous
//
#include <hip/hip_runtime.h>

#define STEPS 30
#define HID 32
#define TPB 256
#define EPB 256                  // 4 waves x 2 groups x 32 elems: 2 chains per wave (ILP)
#define LDS_STRIDE (STEPS + 1)   // 31: odd stride -> conflict-free per-element column reads

typedef float f32x16 __attribute__((ext_vector_type(16)));
typedef __fp16 h8 __attribute__((ext_vector_type(8)));
typedef unsigned int u32x4 __attribute__((ext_vector_type(4)));

// v_cvt_pkrtz_f16_f32 -> packed (lo=x, hi=y) as one 32-bit reg
static __device__ __forceinline__ unsigned int pkrtz_u32(float x, float y) {
    return __builtin_bit_cast(unsigned int, __builtin_amdgcn_cvt_pkrtz(x, y));
}

__global__ __launch_bounds__(TPB, 4) void hedge_kernel(
    const float* __restrict__ S,
    const float* __restrict__ W1,
    const float* __restrict__ b1,
    const float* __restrict__ W2,
    const float* __restrict__ b2,
    const float* __restrict__ a_init,
    float* __restrict__ out)
{
    __shared__ float tile[EPB * LDS_STRIDE];   // 256*31*4 = 31744 B
    const int tid  = threadIdx.x;
    const int lane = tid & 63;
    const int wv   = tid >> 6;                 // wave id 0..3, owns elems 64*wv..64*wv+63
    const long long base = (long long)blockIdx.x * (EPB * STEPS);

    // ---- Stage S tile (256 elems x 30 steps) coalesced via float2 into padded LDS ----
    const float2* S2 = (const float2*)(S + base);
    #pragma unroll
    for (int k = 0; k < (EPB * STEPS) / (2 * TPB); ++k) {   // 15 iters
        int i2 = tid + k * TPB;            // float2 index in [0, 3840)
        float2 v = S2[i2];
        int row = i2 / 15;                 // = (2*i2)/30
        int col = 2 * (i2 - row * 15);     // even, <= 28: pair stays within a row
        float* p = &tile[row * LDS_STRIDE + col];
        p[0] = v.x; p[1] = v.y;
    }

    // ---- A fragment (constant): W1^aug (32 units x K=16), biases in k0 row.
    //      mfma_f32_32x32x16_f16 A layout: row m = lane&31, k = (lane>>5)*8 + {0..7}.
    //      Lanes<32 hold k=0..3 = (wb, wa, wc, we); all other k are 0 -> B garbage slots
    //      are harmless. ----
    const int j = lane & 31;
    const float wbf = b1[j];
    const float waf = W1[0 * HID + j];         // coeff of s
    const float wcf = W1[1 * HID + j];         // coeff of d_prev
    const float wef = W1[2 * HID + j];         // coeff of h
    u32x4 av;
    if (lane < 32) {
        av[0] = pkrtz_u32(wbf, waf);           // k0=bias-row(1), k1=s
        av[1] = pkrtz_u32(wcf, wef);           // k2=d, k3=h
        av[2] = 0u; av[3] = 0u;                // k4..7 dead
    } else {
        av[0] = 0u; av[1] = 0u; av[2] = 0u; av[3] = 0u;   // k8..15 dead
    }
    const h8 afrag = __builtin_bit_cast(h8, av);

    // ---- Per-lane W2 slice matching the C/D row map:
    //      row(reg r) = (r&3) + 8*(r>>2) + 4*(lane>>5) ----
    const int rbase = 4 * (lane >> 5);
    float w2r[16];
    #pragma unroll
    for (int r = 0; r < 16; ++r)
        w2r[r] = W2[(r & 3) + 8 * (r >> 2) + rbase];

    const float bias2 = b2[0];
    const float d_init = a_init[0];
    float dA = d_init, hA = 0.0f;              // chain A state (fp32)
    float dB = d_init, hB = 0.0f;              // chain B state (fp32)
    const f32x16 zero16 = {0.f};               // loop-invariant C operand
    __syncthreads();

    // ---- Recurrence: one wave = 2 independent 32-element groups, interleaved.
    //      While chain A waits on MFMA/shfl latency, chain B's VALU issues. ----
    const int erow = 64 * wv + (lane & 31);
    float* myA = &tile[erow * LDS_STRIDE];
    float* myB = &tile[(erow + 32) * LDS_STRIDE];
    #pragma unroll
    for (int t = 0; t < STEPS; ++t) {
        const float sA = myA[t];               // bank (t - lane) mod 32: conflict-free
        const float sB = myB[t];

        u32x4 bvA, bvB;
        bvA[0] = pkrtz_u32(1.0f, sA);          // k0=1 (bias), k1=s
        bvA[1] = pkrtz_u32(dA, hA);            // k2=d, k3=h
        bvA[2] = bvA[0]; bvA[3] = bvA[1];      // dead slots (A zeros)
        bvB[0] = pkrtz_u32(1.0f, sB);
        bvB[1] = pkrtz_u32(dB, hB);
        bvB[2] = bvB[0]; bvB[3] = bvB[1];

        const f32x16 PA = __builtin_amdgcn_mfma_f32_32x32x16_f16(
            afrag, __builtin_bit_cast(h8, bvA), zero16, 0, 0, 0);
        const f32x16 PB = __builtin_amdgcn_mfma_f32_32x32x16_f16(
            afrag, __builtin_bit_cast(h8, bvB), zero16, 0, 0, 0);

        float a0 = 0.f, a1 = 0.f, b0 = 0.f, b1v = 0.f;
        #pragma unroll
        for (int r = 0; r < 16; r += 2) {
            a0  = fmaf(w2r[r + 0], fmaxf(PA[r + 0], 0.f), a0);
            a1  = fmaf(w2r[r + 1], fmaxf(PA[r + 1], 0.f), a1);
            b0  = fmaf(w2r[r + 0], fmaxf(PB[r + 0], 0.f), b0);
            b1v = fmaf(w2r[r + 1], fmaxf(PB[r + 1], 0.f), b1v);
        }
        float partA = a0 + a1;                 // this half-wave's 16 units
        float partB = b0 + b1v;
        partA += __shfl_xor(partA, 32);        // + other half's 16 units
        partB += __shfl_xor(partB, 32);
        const float dnA = bias2 + partA;       // every lane: full d_t for its element
        const float dnB = bias2 + partB;
        hA = fmaf(0.2f, dnA, 0.8f * hA);
        hB = fmaf(0.2f, dnB, 0.8f * hB);
        dA = dnA;
        dB = dnB;
        if (lane < 32) {                       // halves hold identical dn: write once
            myA[t] = dnA;                      // S[t] consumed; slot reused for output
            myB[t] = dnB;
        }
    }
    __syncthreads();

    // ---- Dump outputs coalesced via float2 (same flat layout as S) ----
    float2* O2 = (float2*)(out + base);
    #pragma unroll
    for (int k = 0; k < (EPB * STEPS) / (2 * TPB); ++k) {   // 15 iters
        int i2 = tid + k * TPB;
        int row = i2 / 15;
        int col = 2 * (i2 - row * 15);
        const float* p = &tile[row * LDS_STRIDE + col];
        O2[i2] = make_float2(p[0], p[1]);
    }
}

extern "C" void kernel_launch(void* const* d_in, const int* in_sizes, int n_in,
                              void* d_out, int out_size, void* d_ws, size_t ws_size,
                              hipStream_t stream) {
    const float* S      = (const float*)d_in[0];
    const float* W1     = (const float*)d_in[1];
    const float* b1     = (const float*)d_in[2];
    const float* W2     = (const float*)d_in[3];
    const float* b2     = (const float*)d_in[4];
    const float* a_init = (const float*)d_in[5];
    float* out = (float*)d_out;

    const int batch = in_sizes[0] / STEPS;    // 1048576
    const int grid  = batch / EPB;            // 4096 blocks of 256 elements
    hedge_kernel<<<grid, TPB, 0, stream>>>(S, W1, b1, W2, b2, a_init, out);
}